// Round 5
// baseline (513.774 us; speedup 1.0000x reference)
//
#include <hip/hip_runtime.h>
#include <math.h>

#define EPS 1e-6f
#define LOG2E 1.44269504f
constexpr int D = 128;

typedef short bf16x8 __attribute__((ext_vector_type(8)));
typedef float f32x4  __attribute__((ext_vector_type(4)));
typedef float f32x2  __attribute__((ext_vector_type(2)));
typedef _Float16 h2  __attribute__((ext_vector_type(2)));

__device__ inline unsigned short f2bf(float x) {
    unsigned u = __float_as_uint(x);
    return (unsigned short)((u + 0x7fffu + ((u >> 16) & 1u)) >> 16);
}

__device__ inline float fast_sqrt(float x) {
#if __has_builtin(__builtin_amdgcn_sqrtf)
    return __builtin_amdgcn_sqrtf(x);
#else
    return sqrtf(x);
#endif
}
__device__ inline float fast_exp2(float x) {
#if __has_builtin(__builtin_amdgcn_exp2f)
    return __builtin_amdgcn_exp2f(x);
#else
    return exp2f(x);
#endif
}

__device__ inline h2 as_h2(unsigned u) {
    union { unsigned u; h2 h; } x; x.u = u; return x.h;
}

__device__ inline float dot16(uint4 a0, uint4 a1, uint4 b0, uint4 b1) {
    // dot of 16 fp16 dims, fp32 accumulate
#if __has_builtin(__builtin_amdgcn_fdot2)
    float s = 0.0f;
    s = __builtin_amdgcn_fdot2(as_h2(a0.x), as_h2(b0.x), s, false);
    s = __builtin_amdgcn_fdot2(as_h2(a0.y), as_h2(b0.y), s, false);
    s = __builtin_amdgcn_fdot2(as_h2(a0.z), as_h2(b0.z), s, false);
    s = __builtin_amdgcn_fdot2(as_h2(a0.w), as_h2(b0.w), s, false);
    s = __builtin_amdgcn_fdot2(as_h2(a1.x), as_h2(b1.x), s, false);
    s = __builtin_amdgcn_fdot2(as_h2(a1.y), as_h2(b1.y), s, false);
    s = __builtin_amdgcn_fdot2(as_h2(a1.z), as_h2(b1.z), s, false);
    s = __builtin_amdgcn_fdot2(as_h2(a1.w), as_h2(b1.w), s, false);
    return s;
#else
    float s = 0.0f;
    const unsigned aw[8] = {a0.x, a0.y, a0.z, a0.w, a1.x, a1.y, a1.z, a1.w};
    const unsigned bw[8] = {b0.x, b0.y, b0.z, b0.w, b1.x, b1.y, b1.z, b1.w};
    #pragma unroll
    for (int t = 0; t < 8; ++t) {
        h2 ah = as_h2(aw[t]), bh = as_h2(bw[t]);
        s = fmaf((float)ah.x, (float)bh.x, s);
        s = fmaf((float)ah.y, (float)bh.y, s);
    }
    return s;
#endif
}

// ---- prep: fp32 row -> bf16 row (+eps-norm) and fp16 row (+plain norm) -----
__global__ __launch_bounds__(256)
void prep_kernel(const float* __restrict__ in, int rows, float eps,
                 unsigned* __restrict__ outb, unsigned* __restrict__ outh,
                 unsigned short* __restrict__ outf8,
                 float* __restrict__ norms, float* __restrict__ normsh) {
    int gw = (blockIdx.x * blockDim.x + threadIdx.x) >> 6;
    int lane = threadIdx.x & 63;
    if (gw >= rows) return;
    float2 v = ((const float2*)(in + (size_t)gw * D))[lane];
    outb[(size_t)gw * 64 + lane] = (unsigned)f2bf(v.x) | ((unsigned)f2bf(v.y) << 16);

    float s2 = 0.0f;
    if (outh) {
        union { h2 h; unsigned u; } hx;
        hx.h = h2{(_Float16)v.x, (_Float16)v.y};
        outh[(size_t)gw * 64 + lane] = hx.u;
        const float fx = (float)hx.h.x, fy = (float)hx.h.y;
        s2 = fx * fx + fy * fy;
    }
    if (outf8) {
        int p = __builtin_amdgcn_cvt_pk_fp8_f32(v.x, v.y, 0, false);
        outf8[(size_t)gw * 64 + lane] = (unsigned short)(p & 0xffff);
    }
    float a = v.x + eps, b = v.y + eps;
    float s = a * a + b * b;
    #pragma unroll
    for (int off = 32; off > 0; off >>= 1) {
        s  += __shfl_down(s, off);
        s2 += __shfl_down(s2, off);
    }
    if (lane == 0) {
        norms[gw] = s;
        if (outh) normsh[gw] = s2;
    }
}

// ---- fused dist-GEMM (MFMA bf16, LDS-free) + exp + column reduction --------
// colOut[i] += sum_j exp(bias[j] - (sqrt(normA[j]+normB[i]-2*dot(a_j,b_i)) + EPS))
// Block: 128 j x 128 i, K=128 fully unrolled. Fragments loaded DIRECTLY from
// global in MFMA A/B layout (row*256B + chunk*16B) -- tables are L2-resident,
// L1 absorbs the 2x inter-wave overlap. No LDS tiles, no barriers in the hot
// path -> no vmcnt(0) drain stalls; occupancy bound only by VGPRs.
__global__ __launch_bounds__(256, 3)
void dist_mfma_kernel(const unsigned short* __restrict__ Ab,  // [J,128] bf16
                      const unsigned short* __restrict__ Bb,  // [I,128] bf16
                      const float* __restrict__ normA,
                      const float* __restrict__ normB,
                      const float* __restrict__ bias,
                      float* __restrict__ colOut) {
    __shared__ float red[256];
    const int tid = threadIdx.x;
    const int i0 = blockIdx.x * 128;
    const int j0 = blockIdx.y * 128;
    const int lane = tid & 63;
    const int wave = tid >> 6;
    const int m = lane & 15;
    const int q = lane >> 4;
    const int wj0 = (wave & 1) * 64;
    const int wi0 = (wave >> 1) * 64;

    const char* pA = (const char*)Ab + ((size_t)(j0 + wj0 + m) * 256 + q * 16);
    const char* pB = (const char*)Bb + ((size_t)(i0 + wi0 + m) * 256 + q * 16);

    const f32x4 zero = {0.f, 0.f, 0.f, 0.f};
    f32x4 acc[4][4];
    #pragma unroll
    for (int jt = 0; jt < 4; ++jt)
        #pragma unroll
        for (int it = 0; it < 4; ++it) acc[jt][it] = zero;

    #pragma unroll
    for (int c = 0; c < 4; ++c) {          // k-chunks of 32 (4 x 16B per row)
        bf16x8 af[4], bfr[4];
        #pragma unroll
        for (int jt = 0; jt < 4; ++jt)
            af[jt] = *(const bf16x8*)(pA + jt * (16 * 256) + c * 64);
        #pragma unroll
        for (int it = 0; it < 4; ++it)
            bfr[it] = *(const bf16x8*)(pB + it * (16 * 256) + c * 64);
        #pragma unroll
        for (int jt = 0; jt < 4; ++jt)
            #pragma unroll
            for (int it = 0; it < 4; ++it)
                acc[jt][it] = __builtin_amdgcn_mfma_f32_16x16x32_bf16(
                    af[jt], bfr[it], acc[jt][it], 0, 0, 0);
    }

    // epilogue: d2 -> sqrt -> exp -> column (i) sums
    float nb[4];
    #pragma unroll
    for (int it = 0; it < 4; ++it) nb[it] = normB[i0 + wi0 + it * 16 + m];

    float colsum[4] = {0.f, 0.f, 0.f, 0.f};
    #pragma unroll
    for (int jt = 0; jt < 4; ++jt) {
        const int jb = j0 + wj0 + jt * 16 + q * 4;
        #pragma unroll
        for (int r = 0; r < 4; ++r) {
            const float na = normA[jb + r];
            const float eb = (bias[jb + r] - EPS) * LOG2E;
            #pragma unroll
            for (int it = 0; it < 4; ++it) {
                const float d2 = na + nb[it] - 2.0f * acc[jt][it][r];
                const float dd = fast_sqrt(fmaxf(d2, 0.0f));
                colsum[it] += fast_exp2(eb - dd * LOG2E);
            }
        }
    }
    #pragma unroll
    for (int it = 0; it < 4; ++it) {
        float s = colsum[it];
        s += __shfl_xor(s, 16);
        s += __shfl_xor(s, 32);
        colsum[it] = s;
    }

    if (q == 0) {
        #pragma unroll
        for (int it = 0; it < 4; ++it)
            red[((wave & 1) * 2 + (wave >> 1)) * 64 + it * 16 + m] = colsum[it];
    }
    __syncthreads();
    if (tid < 128) {
        const int ih = tid >> 6, idx = tid & 63;
        const float s = red[(0 * 2 + ih) * 64 + idx] + red[(1 * 2 + ih) * 64 + idx];
        atomicAdd(&colOut[i0 + tid], s);
    }
}

// ---- link (edge) term: fp16 tables, dot-trick, 8 lanes/edge, 8 edges/wave --
__global__ __launch_bounds__(256)
void edge_f16_kernel(const unsigned char* __restrict__ Lh,
                     const unsigned char* __restrict__ Rh,
                     const unsigned char* __restrict__ Uh,
                     const float* __restrict__ nL, const float* __restrict__ nR,
                     const float* __restrict__ nU,
                     const float* __restrict__ rho, const float* __restrict__ nu,
                     const float* __restrict__ tau, const float* __restrict__ w,
                     const int* __restrict__ si, const int* __restrict__ sj,
                     const int* __restrict__ sk, int E,
                     float* __restrict__ out) {
    const int lane = threadIdx.x & 63;
    const int wv = threadIdx.x >> 6;
    const int sub = lane & 7;        // dim chunk: dims [sub*16, sub*16+16)
    const int eg  = lane >> 3;       // edge within wave (0..7)
    const int gwave = blockIdx.x * 4 + wv;
    const int nw = gridDim.x * 4;

    float partial = 0.0f;
    for (int base = gwave * 8; base < E; base += nw * 8) {
        const int e = base + eg;
        const bool valid = (e < E);
        float dlr = 0.0f, dlu = 0.0f;
        int i = 0, j = 0, k = 0;
        if (valid) {
            i = si[e]; j = sj[e]; k = sk[e];
            const uint4* lp = (const uint4*)(Lh + (size_t)i * 256 + sub * 32);
            const uint4* rp = (const uint4*)(Rh + (size_t)j * 256 + sub * 32);
            const uint4* up = (const uint4*)(Uh + (size_t)k * 256 + sub * 32);
            const uint4 l0 = lp[0], l1 = lp[1];
            const uint4 r0 = rp[0], r1 = rp[1];
            const uint4 u0 = up[0], u1 = up[1];
            dlr = dot16(l0, l1, r0, r1);
            dlu = dot16(l0, l1, u0, u1);
        }
        dlr += __shfl_xor(dlr, 1); dlu += __shfl_xor(dlu, 1);
        dlr += __shfl_xor(dlr, 2); dlu += __shfl_xor(dlu, 2);
        dlr += __shfl_xor(dlr, 4); dlu += __shfl_xor(dlu, 4);
        if (valid && sub == 0) {
            const float ni = nL[i];
            const float d2a = ni + nR[j] - 2.0f * dlr;
            const float d2b = ni + nU[k] - 2.0f * dlu;
            partial += w[e] * (rho[i] + nu[j] + tau[k]
                               - fast_sqrt(fmaxf(d2a, 0.0f))
                               - fast_sqrt(fmaxf(d2b, 0.0f)));
        }
    }
    partial += __shfl_xor(partial, 8);
    partial += __shfl_xor(partial, 16);
    partial += __shfl_xor(partial, 32);
    __shared__ float ps[4];
    if (lane == 0) ps[wv] = partial;
    __syncthreads();
    if (threadIdx.x == 0) atomicAdd(out, ps[0] + ps[1] + ps[2] + ps[3]);
}

// ---- fallback edge kernel on fp8 tables (if ws too small for fp16) ---------
__global__ __launch_bounds__(256)
void edge_fp8_kernel(const uint2* __restrict__ Lf8, const uint2* __restrict__ Rf8,
                     const uint2* __restrict__ Uf8,
                     const float* __restrict__ rho, const float* __restrict__ nu,
                     const float* __restrict__ tau, const float* __restrict__ w,
                     const int* __restrict__ si, const int* __restrict__ sj,
                     const int* __restrict__ sk, int E,
                     float* __restrict__ out) {
    const int lane = threadIdx.x & 63;
    const int wv = threadIdx.x >> 6;
    const int sub = lane & 15;
    const int eg  = lane >> 4;
    const int gwave = blockIdx.x * 4 + wv;
    const int nw = gridDim.x * 4;

    float partial = 0.0f;
    for (int base = gwave * 4; base < E; base += nw * 4) {
        const int e = base + eg;
        const bool valid = (e < E);
        float slr = 0.0f, slu = 0.0f;
        int i = 0, j = 0, k = 0;
        if (valid) {
            i = si[e]; j = sj[e]; k = sk[e];
            const uint2 lq = Lf8[(size_t)i * 16 + sub];
            const uint2 rq = Rf8[(size_t)j * 16 + sub];
            const uint2 uq = Uf8[(size_t)k * 16 + sub];
            const f32x2 l0 = __builtin_amdgcn_cvt_pk_f32_fp8((int)lq.x, false);
            const f32x2 l1 = __builtin_amdgcn_cvt_pk_f32_fp8((int)lq.x, true);
            const f32x2 l2 = __builtin_amdgcn_cvt_pk_f32_fp8((int)lq.y, false);
            const f32x2 l3 = __builtin_amdgcn_cvt_pk_f32_fp8((int)lq.y, true);
            const f32x2 r0 = __builtin_amdgcn_cvt_pk_f32_fp8((int)rq.x, false);
            const f32x2 r1 = __builtin_amdgcn_cvt_pk_f32_fp8((int)rq.x, true);
            const f32x2 r2 = __builtin_amdgcn_cvt_pk_f32_fp8((int)rq.y, false);
            const f32x2 r3 = __builtin_amdgcn_cvt_pk_f32_fp8((int)rq.y, true);
            const f32x2 u0 = __builtin_amdgcn_cvt_pk_f32_fp8((int)uq.x, false);
            const f32x2 u1 = __builtin_amdgcn_cvt_pk_f32_fp8((int)uq.x, true);
            const f32x2 u2 = __builtin_amdgcn_cvt_pk_f32_fp8((int)uq.y, false);
            const f32x2 u3 = __builtin_amdgcn_cvt_pk_f32_fp8((int)uq.y, true);
            float d;
            d = l0.x - r0.x; slr = fmaf(d, d, slr);
            d = l0.y - r0.y; slr = fmaf(d, d, slr);
            d = l1.x - r1.x; slr = fmaf(d, d, slr);
            d = l1.y - r1.y; slr = fmaf(d, d, slr);
            d = l2.x - r2.x; slr = fmaf(d, d, slr);
            d = l2.y - r2.y; slr = fmaf(d, d, slr);
            d = l3.x - r3.x; slr = fmaf(d, d, slr);
            d = l3.y - r3.y; slr = fmaf(d, d, slr);
            d = l0.x - u0.x; slu = fmaf(d, d, slu);
            d = l0.y - u0.y; slu = fmaf(d, d, slu);
            d = l1.x - u1.x; slu = fmaf(d, d, slu);
            d = l1.y - u1.y; slu = fmaf(d, d, slu);
            d = l2.x - u2.x; slu = fmaf(d, d, slu);
            d = l2.y - u2.y; slu = fmaf(d, d, slu);
            d = l3.x - u3.x; slu = fmaf(d, d, slu);
            d = l3.y - u3.y; slu = fmaf(d, d, slu);
        }
        #pragma unroll
        for (int off = 1; off < 16; off <<= 1) {
            slr += __shfl_xor(slr, off);
            slu += __shfl_xor(slu, off);
        }
        if (valid && sub == 0)
            partial += w[e] * (rho[i] + nu[j] + tau[k] - fast_sqrt(slr) - fast_sqrt(slu));
    }
    partial += __shfl_xor(partial, 16);
    partial += __shfl_xor(partial, 32);
    __shared__ float ps[4];
    if (lane == 0) ps[wv] = partial;
    __syncthreads();
    if (threadIdx.x == 0) atomicAdd(out, ps[0] + ps[1] + ps[2] + ps[3]);
}

// ---- z_pdist1 = sum_i colRL[i] * exp(rho_i) * colUL[i] ---------------------
__global__ __launch_bounds__(256)
void combine_kernel(const float* __restrict__ colRL,
                    const float* __restrict__ colUL,
                    const float* __restrict__ rho, int nI,
                    float* __restrict__ out) {
    const int t = blockIdx.x * blockDim.x + threadIdx.x;
    float v = 0.0f;
    if (t < nI) v = colRL[t] * __expf(rho[t]) * colUL[t];
    #pragma unroll
    for (int off = 32; off > 0; off >>= 1) v += __shfl_down(v, off);
    __shared__ float ps[4];
    const int lane = threadIdx.x & 63, wv = threadIdx.x >> 6;
    if (lane == 0) ps[wv] = v;
    __syncthreads();
    if (threadIdx.x == 0) atomicAdd(out, -(ps[0] + ps[1] + ps[2] + ps[3]));
}

extern "C" void kernel_launch(void* const* d_in, const int* in_sizes, int n_in,
                              void* d_out, int out_size, void* d_ws, size_t ws_size,
                              hipStream_t stream) {
    (void)n_in; (void)out_size;
    const float* L   = (const float*)d_in[0];
    const float* R   = (const float*)d_in[1];
    const float* U   = (const float*)d_in[2];
    const float* rho = (const float*)d_in[3];
    const float* nu  = (const float*)d_in[4];
    const float* tau = (const float*)d_in[5];
    const float* w   = (const float*)d_in[6];
    const int* si = (const int*)d_in[7];
    const int* sj = (const int*)d_in[8];
    const int* sk = (const int*)d_in[9];
    const int I = in_sizes[3];
    const int J = in_sizes[4];
    const int K = in_sizes[5];
    const int E = in_sizes[6];
    const size_t T = (size_t)I + J + K;

    float* ws     = (float*)d_ws;
    float* colRL  = ws;
    float* colUL  = ws + I;
    float* normL  = ws + 2 * (size_t)I;          // eps-norms (dist)
    float* normR  = normL + I;
    float* normU  = normR + J;
    float* normLh = normU + K;                   // fp16-consistent norms (edge)
    float* normRh = normLh + I;
    float* normUh = normRh + J;
    unsigned short* Lb = (unsigned short*)(normUh + K);   // bf16 tables
    unsigned short* Rb = Lb + (size_t)I * D;
    unsigned short* Ub = Rb + (size_t)J * D;
    unsigned short* Lx = Ub + (size_t)K * D;     // fp16 tables (or fp8 fallback)
    unsigned short* Rx = Lx + (size_t)I * D;
    unsigned short* Ux = Rx + (size_t)J * D;

    const size_t floats_bytes = (2 * (size_t)I + 2 * T) * 4;
    const size_t need_f16 = floats_bytes + T * 256 + T * 256;
    const bool use_f16 = (ws_size >= need_f16);

    hipMemsetAsync(d_out, 0, sizeof(float), stream);
    hipMemsetAsync(colRL, 0, (size_t)2 * I * sizeof(float), stream);

    prep_kernel<<<dim3(I / 4), 256, 0, stream>>>(
        L, I, 0.0f, (unsigned*)Lb, use_f16 ? (unsigned*)Lx : 0,
        use_f16 ? 0 : Lx, normL, normLh);
    prep_kernel<<<dim3(J / 4), 256, 0, stream>>>(
        R, J, EPS, (unsigned*)Rb, use_f16 ? (unsigned*)Rx : 0,
        use_f16 ? 0 : Rx, normR, normRh);
    prep_kernel<<<dim3(K / 4), 256, 0, stream>>>(
        U, K, EPS, (unsigned*)Ub, use_f16 ? (unsigned*)Ux : 0,
        use_f16 ? 0 : Ux, normU, normUh);

    dist_mfma_kernel<<<dim3(I / 128, J / 128), 256, 0, stream>>>(
        Rb, Lb, normR, normL, nu, colRL);
    dist_mfma_kernel<<<dim3(I / 128, K / 128), 256, 0, stream>>>(
        Ub, Lb, normU, normL, tau, colUL);

    if (use_f16) {
        edge_f16_kernel<<<dim3(2048), 256, 0, stream>>>(
            (const unsigned char*)Lx, (const unsigned char*)Rx,
            (const unsigned char*)Ux,
            normLh, normRh, normUh,
            rho, nu, tau, w, si, sj, sk, E, (float*)d_out);
    } else {
        edge_fp8_kernel<<<dim3(2048), 256, 0, stream>>>(
            (const uint2*)Lx, (const uint2*)Rx, (const uint2*)Ux,
            rho, nu, tau, w, si, sj, sk, E, (float*)d_out);
    }

    combine_kernel<<<dim3((I + 255) / 256), 256, 0, stream>>>(
        colRL, colUL, rho, I, (float*)d_out);
}

// Round 6
// 397.252 us; speedup vs baseline: 1.2933x; 1.2933x over previous
//
#include <hip/hip_runtime.h>
#include <math.h>

#define EPS 1e-6f
#define LOG2E 1.44269504f
constexpr int D = 128;

typedef short bf16x8 __attribute__((ext_vector_type(8)));
typedef float f32x4  __attribute__((ext_vector_type(4)));
typedef float f32x2  __attribute__((ext_vector_type(2)));

static __device__ __forceinline__ unsigned short f2bf(float x) {
    unsigned u = __float_as_uint(x);
    return (unsigned short)((u + 0x7fffu + ((u >> 16) & 1u)) >> 16);
}
static __device__ __forceinline__ float fast_sqrt(float x) {
#if __has_builtin(__builtin_amdgcn_sqrtf)
    return __builtin_amdgcn_sqrtf(x);
#else
    return sqrtf(x);
#endif
}
static __device__ __forceinline__ float fast_exp2(float x) {
#if __has_builtin(__builtin_amdgcn_exp2f)
    return __builtin_amdgcn_exp2f(x);
#else
    return exp2f(x);
#endif
}

static __device__ __forceinline__ void dec8(uint2 q, float* f) {
    const f32x2 a = __builtin_amdgcn_cvt_pk_f32_fp8((int)q.x, false);
    const f32x2 b = __builtin_amdgcn_cvt_pk_f32_fp8((int)q.x, true);
    const f32x2 c = __builtin_amdgcn_cvt_pk_f32_fp8((int)q.y, false);
    const f32x2 d = __builtin_amdgcn_cvt_pk_f32_fp8((int)q.y, true);
    f[0] = a.x; f[1] = a.y; f[2] = b.x; f[3] = b.y;
    f[4] = c.x; f[5] = c.y; f[6] = d.x; f[7] = d.y;
}

// ---- prep: fp32 row -> bf16 row + fp8 row; eps-norm (dist) + fp8-norm ------
__global__ __launch_bounds__(256)
void prep_kernel(const float* __restrict__ in, int rows, float eps,
                 unsigned* __restrict__ outb, unsigned short* __restrict__ outf8,
                 float* __restrict__ norms, float* __restrict__ norms8) {
    int gw = (blockIdx.x * blockDim.x + threadIdx.x) >> 6;
    int lane = threadIdx.x & 63;
    if (gw >= rows) return;
    float2 v = ((const float2*)(in + (size_t)gw * D))[lane];
    outb[(size_t)gw * 64 + lane] = (unsigned)f2bf(v.x) | ((unsigned)f2bf(v.y) << 16);
    int p = __builtin_amdgcn_cvt_pk_fp8_f32(v.x, v.y, 0, false);
    outf8[(size_t)gw * 64 + lane] = (unsigned short)(p & 0xffff);
    const f32x2 dec = __builtin_amdgcn_cvt_pk_f32_fp8(p, false);
    float s8 = dec.x * dec.x + dec.y * dec.y;
    float a = v.x + eps, b = v.y + eps;
    float s = a * a + b * b;
    #pragma unroll
    for (int off = 32; off > 0; off >>= 1) {
        s  += __shfl_down(s, off);
        s8 += __shfl_down(s8, off);
    }
    if (lane == 0) { norms[gw] = s; norms8[gw] = s8; }
}

// ---- edge body: fp8 tables, dot-trick, 16 lanes/edge, 4 edges/wave ---------
static __device__ __forceinline__ void edge_body(
    int bid, int nblocks, int tid, float* smem_ps,
    const uint2* __restrict__ Lf8, const uint2* __restrict__ Rf8,
    const uint2* __restrict__ Uf8,
    const float* __restrict__ n8L, const float* __restrict__ n8R,
    const float* __restrict__ n8U,
    const float* __restrict__ rho, const float* __restrict__ nub,
    const float* __restrict__ taub, const float* __restrict__ w,
    const int* __restrict__ si, const int* __restrict__ sj,
    const int* __restrict__ sk, int E, float* __restrict__ out)
{
    const int lane = tid & 63;
    const int wv = tid >> 6;
    const int sub = lane & 15;       // dim chunk: dims [sub*8, sub*8+8)
    const int eg  = lane >> 4;       // edge within wave (0..3)
    const int gwave = bid * 4 + wv;
    const int nw = nblocks * 4;

    float partial = 0.0f;
    for (int base = gwave * 4; base < E; base += nw * 4) {
        const int e = base + eg;
        const bool valid = (e < E);
        float dlr = 0.0f, dlu = 0.0f;
        int i = 0, j = 0, k = 0;
        if (valid) {
            i = si[e]; j = sj[e]; k = sk[e];
            const uint2 lq = Lf8[(size_t)i * 16 + sub];
            const uint2 rq = Rf8[(size_t)j * 16 + sub];
            const uint2 uq = Uf8[(size_t)k * 16 + sub];
            float lf[8], rf[8], uf[8];
            dec8(lq, lf); dec8(rq, rf); dec8(uq, uf);
            #pragma unroll
            for (int t = 0; t < 8; ++t) {
                dlr = fmaf(lf[t], rf[t], dlr);
                dlu = fmaf(lf[t], uf[t], dlu);
            }
        }
        #pragma unroll
        for (int off = 1; off < 16; off <<= 1) {
            dlr += __shfl_xor(dlr, off);
            dlu += __shfl_xor(dlu, off);
        }
        if (valid && sub == 0) {
            const float ni = n8L[i];
            const float d2a = ni + n8R[j] - 2.0f * dlr;
            const float d2b = ni + n8U[k] - 2.0f * dlu;
            partial += w[e] * (rho[i] + nub[j] + taub[k]
                               - fast_sqrt(fmaxf(d2a, 0.0f))
                               - fast_sqrt(fmaxf(d2b, 0.0f)));
        }
    }
    partial += __shfl_xor(partial, 16);
    partial += __shfl_xor(partial, 32);
    if (lane == 0) smem_ps[wv] = partial;
    __syncthreads();
    if (tid == 0)
        atomicAdd(out, smem_ps[0] + smem_ps[1] + smem_ps[2] + smem_ps[3]);
}

// ---- mega kernel: interleaved dist-GEMM blocks + edge blocks ---------------
// Every 3rd block (bx%3==2) is an edge block when edgeBlocks>0 (exact when
// distTotal even and edgeBlocks == distTotal/2). Dist path == round-3 kernel:
// 128x128 tile, BK=64, 32KB XOR-swizzled LDS, fused sqrt/exp/col-reduce.
__global__ __launch_bounds__(256, 4)
void mega_kernel(
    const unsigned short* __restrict__ Rb, const unsigned short* __restrict__ Ub,
    const unsigned short* __restrict__ Lb,
    const float* __restrict__ normR, const float* __restrict__ normU,
    const float* __restrict__ normL,
    const float* __restrict__ nuv, const float* __restrict__ tauv,
    float* __restrict__ colRL, float* __restrict__ colUL,
    int nBx, int nBy0,
    const uint2* __restrict__ Lf8, const uint2* __restrict__ Rf8,
    const uint2* __restrict__ Uf8,
    const float* __restrict__ n8L, const float* __restrict__ n8R,
    const float* __restrict__ n8U,
    const float* __restrict__ rho, const float* __restrict__ nub,
    const float* __restrict__ taub, const float* __restrict__ w,
    const int* __restrict__ si, const int* __restrict__ sj,
    const int* __restrict__ sk, int E, int edgeBlocks,
    float* __restrict__ out)
{
    __shared__ __align__(16) unsigned char smem[32768];
    const int bx = blockIdx.x;
    const int tid = threadIdx.x;

    int bid;
    bool isEdge;
    if (edgeBlocks > 0) {
        isEdge = (bx % 3) == 2;
        bid = isEdge ? (bx / 3) : (bx - bx / 3);
    } else {
        isEdge = false;
        bid = bx;
    }

    if (isEdge) {
        edge_body(bid, edgeBlocks, tid, (float*)smem,
                  Lf8, Rf8, Uf8, n8L, n8R, n8U,
                  rho, nub, taub, w, si, sj, sk, E, out);
        return;
    }

    // ---------------- dist path ----------------
    const int g0 = nBx * nBy0;
    const int z = (bid >= g0) ? 1 : 0;
    const int r = bid - z * g0;
    const unsigned short* Ab = z ? Ub : Rb;
    const float* normA = z ? normU : normR;
    const float* bias  = z ? tauv : nuv;
    float* colOut      = z ? colUL : colRL;
    const int i0 = (r % nBx) * 128;
    const int j0 = (r / nBx) * 128;

    const int lane = tid & 63;
    const int wave = tid >> 6;
    const int m = lane & 15;
    const int q = lane >> 4;
    const int wj0 = (wave & 1) * 64;
    const int wi0 = (wave >> 1) * 64;

    const f32x4 zero = {0.f, 0.f, 0.f, 0.f};
    f32x4 acc[4][4];
    #pragma unroll
    for (int jt = 0; jt < 4; ++jt)
        #pragma unroll
        for (int it = 0; it < 4; ++it) acc[jt][it] = zero;

    #pragma unroll
    for (int k0 = 0; k0 < D; k0 += 64) {
        const uint4* gA = (const uint4*)(Ab + (size_t)j0 * D + k0);
        const uint4* gB = (const uint4*)(Lb + (size_t)i0 * D + k0);
        if (k0) __syncthreads();
        #pragma unroll
        for (int it = 0; it < 4; ++it) {
            const int idx = it * 256 + tid;      // 0..1023
            const int row = idx >> 3;            // 0..127
            const int c8 = idx & 7;
            const int dst = (row << 7) + ((c8 ^ (row & 7)) << 4);
            *(uint4*)(smem + dst)         = gA[row * 16 + c8];
            *(uint4*)(smem + 16384 + dst) = gB[row * 16 + c8];
        }
        __syncthreads();

        #pragma unroll
        for (int c = 0; c < 2; ++c) {
            const int swz = ((c * 4 + q) ^ (m & 7)) << 4;
            bf16x8 af[4], bfr[4];
            #pragma unroll
            for (int jt = 0; jt < 4; ++jt)
                af[jt] = *(const bf16x8*)(smem + ((wj0 + jt * 16 + m) << 7) + swz);
            #pragma unroll
            for (int it = 0; it < 4; ++it)
                bfr[it] = *(const bf16x8*)(smem + 16384 + ((wi0 + it * 16 + m) << 7) + swz);
            #pragma unroll
            for (int jt = 0; jt < 4; ++jt)
                #pragma unroll
                for (int it = 0; it < 4; ++it)
                    acc[jt][it] = __builtin_amdgcn_mfma_f32_16x16x32_bf16(
                        af[jt], bfr[it], acc[jt][it], 0, 0, 0);
        }
    }

    // epilogue: d2 -> sqrt -> exp -> column (i) sums
    float nb[4];
    #pragma unroll
    for (int it = 0; it < 4; ++it) nb[it] = normL[i0 + wi0 + it * 16 + m];

    float colsum[4] = {0.f, 0.f, 0.f, 0.f};
    #pragma unroll
    for (int jt = 0; jt < 4; ++jt) {
        const int jb = j0 + wj0 + jt * 16 + q * 4;
        #pragma unroll
        for (int rr = 0; rr < 4; ++rr) {
            const float na = normA[jb + rr];
            const float eb = (bias[jb + rr] - EPS) * LOG2E;
            #pragma unroll
            for (int it = 0; it < 4; ++it) {
                const float d2 = na + nb[it] - 2.0f * acc[jt][it][rr];
                const float dd = fast_sqrt(fmaxf(d2, 0.0f));
                colsum[it] += fast_exp2(eb - dd * LOG2E);
            }
        }
    }
    #pragma unroll
    for (int it = 0; it < 4; ++it) {
        float s = colsum[it];
        s += __shfl_xor(s, 16);
        s += __shfl_xor(s, 32);
        colsum[it] = s;
    }

    __syncthreads();
    float* red = (float*)smem;
    if (q == 0) {
        #pragma unroll
        for (int it = 0; it < 4; ++it)
            red[((wave & 1) * 2 + (wave >> 1)) * 64 + it * 16 + m] = colsum[it];
    }
    __syncthreads();
    if (tid < 128) {
        const int ih = tid >> 6, idx = tid & 63;
        const float s = red[(0 * 2 + ih) * 64 + idx] + red[(1 * 2 + ih) * 64 + idx];
        atomicAdd(&colOut[i0 + tid], s);
    }
}

// ---- standalone edge kernel (fallback when merge mapping inexact) ----------
__global__ __launch_bounds__(256)
void edge_only_kernel(
    const uint2* __restrict__ Lf8, const uint2* __restrict__ Rf8,
    const uint2* __restrict__ Uf8,
    const float* __restrict__ n8L, const float* __restrict__ n8R,
    const float* __restrict__ n8U,
    const float* __restrict__ rho, const float* __restrict__ nub,
    const float* __restrict__ taub, const float* __restrict__ w,
    const int* __restrict__ si, const int* __restrict__ sj,
    const int* __restrict__ sk, int E, float* __restrict__ out)
{
    __shared__ float ps[4];
    edge_body(blockIdx.x, gridDim.x, threadIdx.x, ps,
              Lf8, Rf8, Uf8, n8L, n8R, n8U,
              rho, nub, taub, w, si, sj, sk, E, out);
}

// ---- z_pdist1 = sum_i colRL[i] * exp(rho_i) * colUL[i] ---------------------
__global__ __launch_bounds__(256)
void combine_kernel(const float* __restrict__ colRL,
                    const float* __restrict__ colUL,
                    const float* __restrict__ rho, int nI,
                    float* __restrict__ out) {
    const int t = blockIdx.x * blockDim.x + threadIdx.x;
    float v = 0.0f;
    if (t < nI) v = colRL[t] * __expf(rho[t]) * colUL[t];
    #pragma unroll
    for (int off = 32; off > 0; off >>= 1) v += __shfl_down(v, off);
    __shared__ float ps[4];
    const int lane = threadIdx.x & 63, wv = threadIdx.x >> 6;
    if (lane == 0) ps[wv] = v;
    __syncthreads();
    if (threadIdx.x == 0) atomicAdd(out, -(ps[0] + ps[1] + ps[2] + ps[3]));
}

extern "C" void kernel_launch(void* const* d_in, const int* in_sizes, int n_in,
                              void* d_out, int out_size, void* d_ws, size_t ws_size,
                              hipStream_t stream) {
    (void)n_in; (void)out_size; (void)ws_size;
    const float* L   = (const float*)d_in[0];
    const float* R   = (const float*)d_in[1];
    const float* U   = (const float*)d_in[2];
    const float* rho = (const float*)d_in[3];
    const float* nu  = (const float*)d_in[4];
    const float* tau = (const float*)d_in[5];
    const float* w   = (const float*)d_in[6];
    const int* si = (const int*)d_in[7];
    const int* sj = (const int*)d_in[8];
    const int* sk = (const int*)d_in[9];
    const int I = in_sizes[3];
    const int J = in_sizes[4];
    const int K = in_sizes[5];
    const int E = in_sizes[6];

    float* ws     = (float*)d_ws;
    float* colRL  = ws;
    float* colUL  = ws + I;
    float* normL  = colUL + I;       // eps-norms for dist
    float* normR  = normL + I;
    float* normU  = normR + J;
    float* n8L    = normU + K;       // fp8-consistent norms for edge
    float* n8R    = n8L + I;
    float* n8U    = n8R + J;
    unsigned short* Lb = (unsigned short*)(n8U + K);      // bf16 tables
    unsigned short* Rb = Lb + (size_t)I * D;
    unsigned short* Ub = Rb + (size_t)J * D;
    unsigned short* Lf8 = Ub + (size_t)K * D;             // fp8 tables (64 ushort/row)
    unsigned short* Rf8 = Lf8 + (size_t)I * 64;
    unsigned short* Uf8 = Rf8 + (size_t)J * 64;

    hipMemsetAsync(d_out, 0, sizeof(float), stream);
    hipMemsetAsync(colRL, 0, (size_t)2 * I * sizeof(float), stream);

    prep_kernel<<<dim3(I / 4), 256, 0, stream>>>(L, I, 0.0f, (unsigned*)Lb, Lf8, normL, n8L);
    prep_kernel<<<dim3(J / 4), 256, 0, stream>>>(R, J, EPS,  (unsigned*)Rb, Rf8, normR, n8R);
    prep_kernel<<<dim3(K / 4), 256, 0, stream>>>(U, K, EPS,  (unsigned*)Ub, Uf8, normU, n8U);

    const int nBx = I / 128, nBy0 = J / 128, nBy1 = K / 128;
    const int distTotal = nBx * (nBy0 + nBy1);
    const bool merged = (distTotal % 2) == 0;
    const int edgeBlocks = merged ? distTotal / 2 : 0;

    mega_kernel<<<dim3(distTotal + edgeBlocks), 256, 0, stream>>>(
        Rb, Ub, Lb, normR, normU, normL, nu, tau, colRL, colUL,
        nBx, nBy0,
        (const uint2*)Lf8, (const uint2*)Rf8, (const uint2*)Uf8,
        n8L, n8R, n8U, rho, nu, tau, w, si, sj, sk, E, edgeBlocks,
        (float*)d_out);

    if (!merged) {
        edge_only_kernel<<<dim3(2048), 256, 0, stream>>>(
            (const uint2*)Lf8, (const uint2*)Rf8, (const uint2*)Uf8,
            n8L, n8R, n8U, rho, nu, tau, w, si, sj, sk, E, (float*)d_out);
    }

    combine_kernel<<<dim3((I + 255) / 256), 256, 0, stream>>>(
        colRL, colUL, rho, I, (float*)d_out);
}

// Round 7
// 302.909 us; speedup vs baseline: 1.6961x; 1.3115x over previous
//
#include <hip/hip_runtime.h>
#include <math.h>

#define EPS 1e-6f
#define LOG2E 1.44269504f
constexpr int D = 128;

typedef short bf16x8 __attribute__((ext_vector_type(8)));
typedef float f32x4  __attribute__((ext_vector_type(4)));
typedef float f32x2  __attribute__((ext_vector_type(2)));

static __device__ __forceinline__ unsigned short f2bf(float x) {
    unsigned u = __float_as_uint(x);
    return (unsigned short)((u + 0x7fffu + ((u >> 16) & 1u)) >> 16);
}
static __device__ __forceinline__ float fast_sqrt(float x) {
#if __has_builtin(__builtin_amdgcn_sqrtf)
    return __builtin_amdgcn_sqrtf(x);
#else
    return sqrtf(x);
#endif
}
static __device__ __forceinline__ float fast_exp2(float x) {
#if __has_builtin(__builtin_amdgcn_exp2f)
    return __builtin_amdgcn_exp2f(x);
#else
    return exp2f(x);
#endif
}

static __device__ __forceinline__ void dec16(uint4 q, float* f) {
    f32x2 t;
    t = __builtin_amdgcn_cvt_pk_f32_fp8((int)q.x, false); f[0]=t.x;  f[1]=t.y;
    t = __builtin_amdgcn_cvt_pk_f32_fp8((int)q.x, true);  f[2]=t.x;  f[3]=t.y;
    t = __builtin_amdgcn_cvt_pk_f32_fp8((int)q.y, false); f[4]=t.x;  f[5]=t.y;
    t = __builtin_amdgcn_cvt_pk_f32_fp8((int)q.y, true);  f[6]=t.x;  f[7]=t.y;
    t = __builtin_amdgcn_cvt_pk_f32_fp8((int)q.z, false); f[8]=t.x;  f[9]=t.y;
    t = __builtin_amdgcn_cvt_pk_f32_fp8((int)q.z, true);  f[10]=t.x; f[11]=t.y;
    t = __builtin_amdgcn_cvt_pk_f32_fp8((int)q.w, false); f[12]=t.x; f[13]=t.y;
    t = __builtin_amdgcn_cvt_pk_f32_fp8((int)q.w, true);  f[14]=t.x; f[15]=t.y;
}

// ---- fused prep: all T rows -> bf16 + fp8 tables + both norm sets; tail ----
// blocks zero colRL/colUL and d_out (so no hipMemsetAsync launches needed).
__global__ __launch_bounds__(256)
void prep_all_kernel(const float* __restrict__ L, const float* __restrict__ R,
                     const float* __restrict__ U, int I, int J, int nPrep,
                     unsigned* __restrict__ outb, unsigned short* __restrict__ outf8,
                     float* __restrict__ norms, float* __restrict__ norms8,
                     float* __restrict__ zeroPtr, int nZeroFloats,
                     float* __restrict__ d_out) {
    const int b = blockIdx.x;
    const int tid = threadIdx.x;
    if (b >= nPrep) {
        const int off = ((b - nPrep) * 256 + tid) * 4;
        if (off < nZeroFloats) {
            float4 zz = {0.f, 0.f, 0.f, 0.f};
            *(float4*)(zeroPtr + off) = zz;
        }
        if (b == nPrep && tid == 0) *d_out = 0.0f;
        return;
    }
    const int row = b * 4 + (tid >> 6);
    const int lane = tid & 63;
    const float* src;
    float eps;
    if (row < I)          { src = L + (size_t)row * D;           eps = 0.0f; }
    else if (row < I + J) { src = R + (size_t)(row - I) * D;     eps = EPS; }
    else                  { src = U + (size_t)(row - I - J) * D; eps = EPS; }
    const float2 v = ((const float2*)src)[lane];
    outb[(size_t)row * 64 + lane] = (unsigned)f2bf(v.x) | ((unsigned)f2bf(v.y) << 16);
    const int p = __builtin_amdgcn_cvt_pk_fp8_f32(v.x, v.y, 0, false);
    outf8[(size_t)row * 64 + lane] = (unsigned short)(p & 0xffff);
    const f32x2 dec = __builtin_amdgcn_cvt_pk_f32_fp8(p, false);
    float s8 = dec.x * dec.x + dec.y * dec.y;
    const float a = v.x + eps, bb = v.y + eps;
    float s = a * a + bb * bb;
    #pragma unroll
    for (int off = 32; off > 0; off >>= 1) {
        s  += __shfl_down(s, off);
        s8 += __shfl_down(s8, off);
    }
    if (lane == 0) { norms[row] = s; norms8[row] = s8; }
}

// ---- edge body: fp8, dot-trick, 8 lanes/edge, 8 edges/wave, SW-pipelined ---
static __device__ __forceinline__ void edge_body(
    int bid, int nblocks, int tid, float* smem_ps,
    const uint4* __restrict__ Lf8, const uint4* __restrict__ Rf8,
    const uint4* __restrict__ Uf8,
    const float* __restrict__ n8L, const float* __restrict__ n8R,
    const float* __restrict__ n8U,
    const float* __restrict__ rho, const float* __restrict__ nub,
    const float* __restrict__ taub, const float* __restrict__ w,
    const int* __restrict__ si, const int* __restrict__ sj,
    const int* __restrict__ sk, int E, float* __restrict__ out)
{
    const int lane = tid & 63;
    const int wv = tid >> 6;
    const int sub = lane & 7;        // 16B chunk: dims [sub*16, sub*16+16)
    const int eg  = lane >> 3;       // edge within wave (0..7)
    const int gwave = bid * 4 + wv;
    const int nw = nblocks * 4;
    const int stride = nw * 8;

    float partial = 0.0f;

    int base = gwave * 8;
    int e = base + eg;
    bool v = (base < E) && (e < E);
    uint4 lq = {}, rq = {}, uq = {};
    float bsum = 0.f, wt = 0.f, nlr = 0.f, nlu = 0.f;
    if (v) {
        const int i = si[e], j = sj[e], k = sk[e];
        lq = Lf8[(size_t)i * 8 + sub];
        rq = Rf8[(size_t)j * 8 + sub];
        uq = Uf8[(size_t)k * 8 + sub];
        if (sub == 0) {
            bsum = rho[i] + nub[j] + taub[k];
            wt = w[e];
            const float nl = n8L[i];
            nlr = nl + n8R[j];
            nlu = nl + n8U[k];
        }
    }

    while (base < E) {
        const int nbase = base + stride;
        // ---- prefetch next iteration (loads issue before current compute) --
        const int e2 = nbase + eg;
        const bool v2 = (nbase < E) && (e2 < E);
        uint4 lq2 = {}, rq2 = {}, uq2 = {};
        float bsum2 = 0.f, wt2 = 0.f, nlr2 = 0.f, nlu2 = 0.f;
        if (v2) {
            const int i2 = si[e2], j2 = sj[e2], k2 = sk[e2];
            lq2 = Lf8[(size_t)i2 * 8 + sub];
            rq2 = Rf8[(size_t)j2 * 8 + sub];
            uq2 = Uf8[(size_t)k2 * 8 + sub];
            if (sub == 0) {
                bsum2 = rho[i2] + nub[j2] + taub[k2];
                wt2 = w[e2];
                const float nl2 = n8L[i2];
                nlr2 = nl2 + n8R[j2];
                nlu2 = nl2 + n8U[k2];
            }
        }
        // ---- compute current ----
        float dlr = 0.f, dlu = 0.f;
        if (v) {
            float lf[16], rf[16], uf[16];
            dec16(lq, lf); dec16(rq, rf); dec16(uq, uf);
            #pragma unroll
            for (int t = 0; t < 16; ++t) {
                dlr = fmaf(lf[t], rf[t], dlr);
                dlu = fmaf(lf[t], uf[t], dlu);
            }
        }
        dlr += __shfl_xor(dlr, 1); dlu += __shfl_xor(dlu, 1);
        dlr += __shfl_xor(dlr, 2); dlu += __shfl_xor(dlu, 2);
        dlr += __shfl_xor(dlr, 4); dlu += __shfl_xor(dlu, 4);
        if (v && sub == 0) {
            const float d2a = nlr - 2.0f * dlr;
            const float d2b = nlu - 2.0f * dlu;
            partial += wt * (bsum - fast_sqrt(fmaxf(d2a, 0.f))
                                  - fast_sqrt(fmaxf(d2b, 0.f)));
        }
        // ---- rotate ----
        base = nbase; v = v2;
        lq = lq2; rq = rq2; uq = uq2;
        bsum = bsum2; wt = wt2; nlr = nlr2; nlu = nlu2;
    }
    partial += __shfl_xor(partial, 8);
    partial += __shfl_xor(partial, 16);
    partial += __shfl_xor(partial, 32);
    if (lane == 0) smem_ps[wv] = partial;
    __syncthreads();
    if (tid == 0)
        atomicAdd(out, smem_ps[0] + smem_ps[1] + smem_ps[2] + smem_ps[3]);
}

// ---- mega kernel: interleaved dist-GEMM blocks + edge blocks ---------------
__global__ __launch_bounds__(256, 4)
void mega_kernel(
    const unsigned short* __restrict__ Rb, const unsigned short* __restrict__ Ub,
    const unsigned short* __restrict__ Lb,
    const float* __restrict__ normR, const float* __restrict__ normU,
    const float* __restrict__ normL,
    const float* __restrict__ nuv, const float* __restrict__ tauv,
    float* __restrict__ colRL, float* __restrict__ colUL,
    int nBx, int nBy0,
    const uint4* __restrict__ Lf8, const uint4* __restrict__ Rf8,
    const uint4* __restrict__ Uf8,
    const float* __restrict__ n8L, const float* __restrict__ n8R,
    const float* __restrict__ n8U,
    const float* __restrict__ rho, const float* __restrict__ nub,
    const float* __restrict__ taub, const float* __restrict__ w,
    const int* __restrict__ si, const int* __restrict__ sj,
    const int* __restrict__ sk, int E, int edgeBlocks,
    float* __restrict__ out)
{
    __shared__ __align__(16) unsigned char smem[32768];
    const int bx = blockIdx.x;
    const int tid = threadIdx.x;

    int bid;
    bool isEdge;
    if (edgeBlocks > 0) {
        isEdge = (bx % 3) == 2;
        bid = isEdge ? (bx / 3) : (bx - bx / 3);
    } else {
        isEdge = false;
        bid = bx;
    }

    if (isEdge) {
        edge_body(bid, edgeBlocks, tid, (float*)smem,
                  Lf8, Rf8, Uf8, n8L, n8R, n8U,
                  rho, nub, taub, w, si, sj, sk, E, out);
        return;
    }

    // ---------------- dist path (proven round-3 kernel) ----------------
    const int g0 = nBx * nBy0;
    const int z = (bid >= g0) ? 1 : 0;
    const int r = bid - z * g0;
    const unsigned short* Ab = z ? Ub : Rb;
    const float* normA = z ? normU : normR;
    const float* bias  = z ? tauv : nuv;
    float* colOut      = z ? colUL : colRL;
    const int i0 = (r % nBx) * 128;
    const int j0 = (r / nBx) * 128;

    const int lane = tid & 63;
    const int wave = tid >> 6;
    const int m = lane & 15;
    const int q = lane >> 4;
    const int wj0 = (wave & 1) * 64;
    const int wi0 = (wave >> 1) * 64;

    const f32x4 zero = {0.f, 0.f, 0.f, 0.f};
    f32x4 acc[4][4];
    #pragma unroll
    for (int jt = 0; jt < 4; ++jt)
        #pragma unroll
        for (int it = 0; it < 4; ++it) acc[jt][it] = zero;

    #pragma unroll
    for (int k0 = 0; k0 < D; k0 += 64) {
        const uint4* gA = (const uint4*)(Ab + (size_t)j0 * D + k0);
        const uint4* gB = (const uint4*)(Lb + (size_t)i0 * D + k0);
        if (k0) __syncthreads();
        #pragma unroll
        for (int it = 0; it < 4; ++it) {
            const int idx = it * 256 + tid;
            const int row = idx >> 3;
            const int c8 = idx & 7;
            const int dst = (row << 7) + ((c8 ^ (row & 7)) << 4);
            *(uint4*)(smem + dst)         = gA[row * 16 + c8];
            *(uint4*)(smem + 16384 + dst) = gB[row * 16 + c8];
        }
        __syncthreads();

        #pragma unroll
        for (int c = 0; c < 2; ++c) {
            const int swz = ((c * 4 + q) ^ (m & 7)) << 4;
            bf16x8 af[4], bfr[4];
            #pragma unroll
            for (int jt = 0; jt < 4; ++jt)
                af[jt] = *(const bf16x8*)(smem + ((wj0 + jt * 16 + m) << 7) + swz);
            #pragma unroll
            for (int it = 0; it < 4; ++it)
                bfr[it] = *(const bf16x8*)(smem + 16384 + ((wi0 + it * 16 + m) << 7) + swz);
            #pragma unroll
            for (int jt = 0; jt < 4; ++jt)
                #pragma unroll
                for (int it = 0; it < 4; ++it)
                    acc[jt][it] = __builtin_amdgcn_mfma_f32_16x16x32_bf16(
                        af[jt], bfr[it], acc[jt][it], 0, 0, 0);
        }
    }

    float nb[4];
    #pragma unroll
    for (int it = 0; it < 4; ++it) nb[it] = normL[i0 + wi0 + it * 16 + m];

    float colsum[4] = {0.f, 0.f, 0.f, 0.f};
    #pragma unroll
    for (int jt = 0; jt < 4; ++jt) {
        const int jb = j0 + wj0 + jt * 16 + q * 4;
        #pragma unroll
        for (int rr = 0; rr < 4; ++rr) {
            const float na = normA[jb + rr];
            const float eb = (bias[jb + rr] - EPS) * LOG2E;
            #pragma unroll
            for (int it = 0; it < 4; ++it) {
                const float d2 = na + nb[it] - 2.0f * acc[jt][it][rr];
                const float dd = fast_sqrt(fmaxf(d2, 0.0f));
                colsum[it] += fast_exp2(eb - dd * LOG2E);
            }
        }
    }
    #pragma unroll
    for (int it = 0; it < 4; ++it) {
        float s = colsum[it];
        s += __shfl_xor(s, 16);
        s += __shfl_xor(s, 32);
        colsum[it] = s;
    }

    __syncthreads();
    float* red = (float*)smem;
    if (q == 0) {
        #pragma unroll
        for (int it = 0; it < 4; ++it)
            red[((wave & 1) * 2 + (wave >> 1)) * 64 + it * 16 + m] = colsum[it];
    }
    __syncthreads();
    if (tid < 128) {
        const int ih = tid >> 6, idx = tid & 63;
        const float s = red[(0 * 2 + ih) * 64 + idx] + red[(1 * 2 + ih) * 64 + idx];
        atomicAdd(&colOut[i0 + tid], s);
    }
}

// ---- standalone edge kernel (fallback when merge mapping inexact) ----------
__global__ __launch_bounds__(256)
void edge_only_kernel(
    const uint4* __restrict__ Lf8, const uint4* __restrict__ Rf8,
    const uint4* __restrict__ Uf8,
    const float* __restrict__ n8L, const float* __restrict__ n8R,
    const float* __restrict__ n8U,
    const float* __restrict__ rho, const float* __restrict__ nub,
    const float* __restrict__ taub, const float* __restrict__ w,
    const int* __restrict__ si, const int* __restrict__ sj,
    const int* __restrict__ sk, int E, float* __restrict__ out)
{
    __shared__ float ps[4];
    edge_body(blockIdx.x, gridDim.x, threadIdx.x, ps,
              Lf8, Rf8, Uf8, n8L, n8R, n8U,
              rho, nub, taub, w, si, sj, sk, E, out);
}

// ---- z_pdist1 = sum_i colRL[i] * exp(rho_i) * colUL[i] ---------------------
__global__ __launch_bounds__(256)
void combine_kernel(const float* __restrict__ colRL,
                    const float* __restrict__ colUL,
                    const float* __restrict__ rho, int nI,
                    float* __restrict__ out) {
    const int t = blockIdx.x * blockDim.x + threadIdx.x;
    float v = 0.0f;
    if (t < nI) v = colRL[t] * __expf(rho[t]) * colUL[t];
    #pragma unroll
    for (int off = 32; off > 0; off >>= 1) v += __shfl_down(v, off);
    __shared__ float ps[4];
    const int lane = threadIdx.x & 63, wv = threadIdx.x >> 6;
    if (lane == 0) ps[wv] = v;
    __syncthreads();
    if (threadIdx.x == 0) atomicAdd(out, -(ps[0] + ps[1] + ps[2] + ps[3]));
}

extern "C" void kernel_launch(void* const* d_in, const int* in_sizes, int n_in,
                              void* d_out, int out_size, void* d_ws, size_t ws_size,
                              hipStream_t stream) {
    (void)n_in; (void)out_size; (void)ws_size;
    const float* L   = (const float*)d_in[0];
    const float* R   = (const float*)d_in[1];
    const float* U   = (const float*)d_in[2];
    const float* rho = (const float*)d_in[3];
    const float* nu  = (const float*)d_in[4];
    const float* tau = (const float*)d_in[5];
    const float* w   = (const float*)d_in[6];
    const int* si = (const int*)d_in[7];
    const int* sj = (const int*)d_in[8];
    const int* sk = (const int*)d_in[9];
    const int I = in_sizes[3];
    const int J = in_sizes[4];
    const int K = in_sizes[5];
    const int E = in_sizes[6];
    const int T = I + J + K;

    float* ws     = (float*)d_ws;
    float* colRL  = ws;                   // I
    float* colUL  = ws + I;               // I
    float* normL  = colUL + I;            // T eps-norms (normL,normR,normU contiguous)
    float* normR  = normL + I;
    float* normU  = normR + J;
    float* n8L    = normU + K;            // T fp8-norms (contiguous)
    float* n8R    = n8L + I;
    float* n8U    = n8R + J;
    unsigned short* Lb = (unsigned short*)(n8U + K);      // bf16 tables (contiguous)
    unsigned short* Rb = Lb + (size_t)I * D;
    unsigned short* Ub = Rb + (size_t)J * D;
    unsigned short* Lf8 = Ub + (size_t)K * D;             // fp8 tables (contiguous)
    unsigned short* Rf8 = Lf8 + (size_t)I * 64;
    unsigned short* Uf8 = Rf8 + (size_t)J * 64;

    // one fused prep launch: tables + norms + zeroing of colRL/colUL/d_out
    const int nPrep = T / 4;
    const int nZero = (2 * I + 1023) / 1024;
    prep_all_kernel<<<dim3(nPrep + nZero), 256, 0, stream>>>(
        L, R, U, I, J, nPrep,
        (unsigned*)Lb, Lf8, normL, n8L,
        colRL, 2 * I, (float*)d_out);

    const int nBx = I / 128, nBy0 = J / 128, nBy1 = K / 128;
    const int distTotal = nBx * (nBy0 + nBy1);
    const bool merged = (distTotal % 2) == 0;
    const int edgeBlocks = merged ? distTotal / 2 : 0;

    mega_kernel<<<dim3(distTotal + edgeBlocks), 256, 0, stream>>>(
        Rb, Ub, Lb, normR, normU, normL, nu, tau, colRL, colUL,
        nBx, nBy0,
        (const uint4*)Lf8, (const uint4*)Rf8, (const uint4*)Uf8,
        n8L, n8R, n8U, rho, nu, tau, w, si, sj, sk, E, edgeBlocks,
        (float*)d_out);

    if (!merged) {
        edge_only_kernel<<<dim3(2048), 256, 0, stream>>>(
            (const uint4*)Lf8, (const uint4*)Rf8, (const uint4*)Uf8,
            n8L, n8R, n8U, rho, nu, tau, w, si, sj, sk, E, (float*)d_out);
    }

    combine_kernel<<<dim3((I + 255) / 256), 256, 0, stream>>>(
        colRL, colUL, rho, I, (float*)d_out);
}